// Round 1
// 60.814 us; speedup vs baseline: 1.0085x; 1.0085x over previous
//
#include <hip/hip_runtime.h>

// Heisenberg-picture evaluation (same verified math as previous round):
//   final Z on qubit j -> gz_j = cos(w1_j) cos th_j
//   final Y on qubit j -> gy_j = -sin(w1_j) cos th_j
//   final X on qubit j -> X_j  = sin th_j
// with th_j = x_j*pi/2; c_j,s_j = cos/sin of FULL layer-2 angles.
//
// This version: 2 vertically-adjacent patches per thread.
//  - loads: 4x float2, lane-contiguous (512B/wave/instr)
//  - stores: 2x float4, lane-contiguous (1KB/wave/instr; patches are
//    128 output rows apart so each store is dense across the wave)
//  - the 16 wave-uniform weight transcendentals + cc/ss/cs/sc products
//    are computed once per thread, amortized over both patches.

__global__ __launch_bounds__(256) void qlayer_kernel(
    const float* __restrict__ x,     // (32, 256, 256, 1)
    const float* __restrict__ qw,    // (2, 4)
    float* __restrict__ out,         // (32, 128, 128, 4)
    int n_pairs)
{
    int n = blockIdx.x * blockDim.x + threadIdx.x;
    if (n >= n_pairs) return;

    int ow  = n & 127;          // output column
    int ohh = (n >> 7) & 63;    // pair of output rows: oh = 2*ohh, 2*ohh+1
    int b   = n >> 13;          // batch

    // ---- issue all global loads first (overlap latency with weight trig) ----
    const float* base = x + ((size_t)(b * 256 + 4 * ohh) * 256 + 2 * ow);
    float2 r0 = *(const float2*)(base);         // input rows 4ohh .. 4ohh+3
    float2 r1 = *(const float2*)(base + 256);
    float2 r2 = *(const float2*)(base + 512);
    float2 r3 = *(const float2*)(base + 768);

    // ---- weight trig: FULL angles, rev = w/(2*pi). Wave-uniform. ----
    const float INV2PI = 0.15915494309189535f;
    float C1[4], S1[4], C2[4], S2[4];
#pragma unroll
    for (int j = 0; j < 4; ++j) {
        float w1 = qw[j]     * INV2PI;   // layer 1 (applied first)
        float w2 = qw[4 + j] * INV2PI;   // layer 2
        S1[j] = __builtin_amdgcn_sinf(w1);
        C1[j] = __builtin_amdgcn_cosf(w1);
        S2[j] = __builtin_amdgcn_sinf(w2);
        C2[j] = __builtin_amdgcn_cosf(w2);
    }
    // weight-only products (uniform), hoisted out of the per-patch body
    float cc = C2[0] * C2[3], ss = S2[0] * S2[3];
    float cs = C2[0] * S2[3], sc = S2[0] * C2[3];

    float xin[2][4] = { { r0.x, r0.y, r1.x, r1.y },     // patch a (oh = 2ohh)
                        { r2.x, r2.y, r3.x, r3.y } };   // patch b (oh = 2ohh+1)
    float4 outv[2];

#pragma unroll
    for (int p = 0; p < 2; ++p) {
        // th_j = x_j*pi/2 -> revolutions = x_j * 0.25 (exact pow2 scale)
        float Cth[4], Sth[4];
#pragma unroll
        for (int j = 0; j < 4; ++j) {
            float r = xin[p][j] * 0.25f;
            Sth[j] = __builtin_amdgcn_sinf(r);
            Cth[j] = __builtin_amdgcn_cosf(r);
        }

        float gz[4], gy[4], X[4];
#pragma unroll
        for (int j = 0; j < 4; ++j) {
            gz[j] = C1[j] * Cth[j];
            gy[j] = -S1[j] * Cth[j];
            X[j]  = Sth[j];
        }

        // ---- z1:  Z1 -> Z0 Z1 -> 4 strings ----
        float a0  = C2[0] * gz[0];
        float b0  = S2[0] * gy[0];
        float in1 = fmaf(b0, X[1], a0);        // c0 gz0 + s0 gy0 X1
        float in2 = fmaf(a0, X[1], b0);        // c0 gz0 X1 + s0 gy0
        float z1  = gz[3] * fmaf(S2[1] * gy[2], in2, C2[1] * gz[2] * in1);

        // ---- shared for z0/z2:  P,Q,R,T over qubits 2,3 ----
        float m23a = X[2] * gz[3];
        float m23b = X[2] * gy[3];
        float P = fmaf(S2[2], m23b,  C2[2] * gz[3]);   // c2 gz3 + s2 X2 gy3
        float R = fmaf(C2[2], m23a,  S2[2] * gy[3]);   // c2 X2 gz3 + s2 gy3
        float Q = fmaf(S2[2], m23a, -C2[2] * gy[3]);   // s2 X2 gz3 - c2 gy3
        float T = fmaf(C2[2], m23b, -S2[2] * gz[3]);   // c2 X2 gy3 - s2 gz3

        float u1 = C2[1] * gz[1], u2 = S2[1] * gy[1];
        float u3 = C2[1] * gy[1], u4 = S2[1] * gz[1];
        float M1 = fmaf(u2, R, u1 * P);                // c1 gz1 P + s1 gy1 R
        float M2 = fmaf(u4, T, u3 * Q);                // c1 gy1 Q + s1 gz1 T
        float M3 = fmaf(-u4, R, u3 * P);               // c1 gy1 P - s1 gz1 R

        // z0 = c3 gz0 M1 + s3 gy0 M2
        float z0 = fmaf(S2[3] * gy[0], M2, C2[3] * gz[0] * M1);
        // z2 = c0 M1 + s0 X0 M3
        float z2 = fmaf(S2[0] * X[0], M3, C2[0] * M1);

        // ---- z3: 16 strings, factorized over qubits 2,3 then 0,1 ----
        float m2a = X[3] * gz[2];
        float m2b = X[3] * gy[2];
        float U  = fmaf(S2[2], m2b,  C2[2] * gz[2]);   // c2 gz2 + s2 gy2 X3
        float V  = fmaf(C2[2], m2a,  S2[2] * gy[2]);   // c2 gz2 X3 + s2 gy2
        float W  = fmaf(-S2[2], m2a, C2[2] * gy[2]);   // c2 gy2 - s2 gz2 X3
        float Xp = fmaf(C2[2], m2b, -S2[2] * gz[2]);   // c2 gy2 X3 - s2 gz2

        float A  = fmaf(-ss, V,  cc * U);
        float Bq = fmaf(-ss, Xp, cc * W);
        float D  = fmaf(sc, W,  cs * Xp);
        float E  = fmaf(sc, U,  cs * V);
        float t1 = fmaf(S2[1] * X[1], Bq, C2[1] * A);
        float t2 = fmaf(C2[1] * X[1], E,  S2[1] * D);
        float z3 = fmaf(gy[0], t2, gz[0] * t1);

        outv[p] = make_float4(z0, z1, z2, z3);
    }

    // out rows 2ohh and 2ohh+1 are 128*4 floats apart
    size_t oidx = ((size_t)(b * 128 + 2 * ohh) * 128 + ow) * 4;
    *(float4*)(out + oidx)       = outv[0];
    *(float4*)(out + oidx + 512) = outv[1];
}

extern "C" void kernel_launch(void* const* d_in, const int* in_sizes, int n_in,
                              void* d_out, int out_size, void* d_ws, size_t ws_size,
                              hipStream_t stream) {
    const float* x  = (const float*)d_in[0];
    const float* qw = (const float*)d_in[1];
    float* out = (float*)d_out;
    // fixed problem size: 32*128*128 = 524288 patches, 2 per thread
    int n_pairs = 32 * 64 * 128;  // 262144 threads
    dim3 block(256);
    dim3 grid((n_pairs + 255) / 256);
    hipLaunchKernelGGL(qlayer_kernel, grid, block, 0, stream, x, qw, out, n_pairs);
}